// Round 1
// baseline (289.888 us; speedup 1.0000x reference)
//
#include <hip/hip_runtime.h>
#include <hip/hip_bf16.h>

// ---- problem constants ----
#define NCLS   19
#define CACHE  5000
#define CPAD   5008          // 313 * 16, padded class stride (cols)
#define NTILE  313           // 16-col tiles per class
#define DDIM   256
#define NANCH  102
#define NVIEW  10
#define NROWS  1020          // NVIEW * NANCH
#define MPAD   1024
#define NSUB   7
#define NCHUNK (NCLS*NSUB)   // 133
#define INVT   14.285714285714286f  // 1/0.07

using bf16x8 = __attribute__((ext_vector_type(8))) __bf16;
using f32x4  = __attribute__((ext_vector_type(4))) float;
using u16x8  = __attribute__((ext_vector_type(8))) unsigned short;

static __device__ __forceinline__ unsigned short f2bf(float x) {
    unsigned int u = __float_as_uint(x);
    unsigned int r = (u + 0x7FFFu + ((u >> 16) & 1u)) >> 16;
    return (unsigned short)r;
}

// ---- convert queue f32 [19][5000][256] -> bf16 [19][5008][256], pad rows = 0 ----
__global__ void conv_queue(const float* __restrict__ Qf, unsigned short* __restrict__ Qbf) {
    size_t i = (size_t)blockIdx.x * blockDim.x + threadIdx.x;   // one per 8 elems
    size_t NE = (size_t)NCLS * CPAD * DDIM / 8;
    if (i >= NE) return;
    size_t e0 = i * 8;
    int k  = (int)(e0 & (DDIM - 1));
    size_t cj = e0 >> 8;                 // cls*CPAD + j
    int cls = (int)(cj / CPAD);
    int j   = (int)(cj - (size_t)cls * CPAD);
    u16x8 out;
    if (j < CACHE) {
        const float* src = Qf + ((size_t)cls * CACHE + j) * DDIM + k;
        float4 v0 = *reinterpret_cast<const float4*>(src);
        float4 v1 = *reinterpret_cast<const float4*>(src + 4);
        out[0]=f2bf(v0.x); out[1]=f2bf(v0.y); out[2]=f2bf(v0.z); out[3]=f2bf(v0.w);
        out[4]=f2bf(v1.x); out[5]=f2bf(v1.y); out[6]=f2bf(v1.z); out[7]=f2bf(v1.w);
    } else {
        for (int q=0;q<8;++q) out[q]=0;
    }
    *reinterpret_cast<u16x8*>(Qbf + e0) = out;
}

// ---- convert anchors: view-major [1024][256] bf16, rows >= 1020 zero ----
__global__ void conv_anchor(const float* __restrict__ X, unsigned short* __restrict__ Abf) {
    int n = blockIdx.x;     // 0..1023
    int k = threadIdx.x;    // 0..255
    float v = 0.f;
    if (n < NROWS) {
        int vv = n / NANCH, a = n - vv * NANCH;
        v = X[((size_t)a * NVIEW + vv) * DDIM + k];
    }
    Abf[(size_t)n * DDIM + k] = f2bf(v);
}

// ---- pass 1: GEMM + exp accumulation (negatives) + positive-logit store ----
__global__ __launch_bounds__(512) void pass1_kernel(
    const unsigned short* __restrict__ Abf, const unsigned short* __restrict__ Qbf,
    const int* __restrict__ y, float* __restrict__ partials, float* __restrict__ poslog)
{
    int b   = blockIdx.x;
    int rt  = b / (NCLS * NSUB);
    int rem = b - rt * (NCLS * NSUB);
    int cls = rem / NSUB;
    int sub = rem - cls * NSUB;
    int t0 = (NTILE * sub) / NSUB, t1 = (NTILE * (sub + 1)) / NSUB;

    int tid = threadIdx.x;
    int wave = tid >> 6, lane = tid & 63;
    int wrb = rt * 256 + wave * 32;
    int lg = lane >> 4;       // 0..3
    int lm = lane & 15;       // 0..15

    // A fragments: row = lane&15, k = (lane>>4)*8 + j, contiguous 8 bf16 = 16B
    bf16x8 afrag[2][8];
    #pragma unroll
    for (int f = 0; f < 2; ++f)
        #pragma unroll
        for (int kk = 0; kk < 8; ++kk)
            afrag[f][kk] = *reinterpret_cast<const bf16x8*>(
                Abf + (size_t)(wrb + f * 16 + lm) * DDIM + kk * 32 + lg * 8);

    bool ispos[2][4];
    int  rowidx[2][4];
    #pragma unroll
    for (int f = 0; f < 2; ++f)
        #pragma unroll
        for (int r = 0; r < 4; ++r) {
            int row = wrb + f * 16 + lg * 4 + r;   // C layout: row=(lane>>4)*4+reg
            rowidx[f][r] = row;
            int rc = (row < NROWS) ? y[row % NANCH] : -1;
            ispos[f][r] = (rc == cls);
        }

    float negacc[2][4] = {};

    for (int t = t0; t < t1; ++t) {
        const unsigned short* qb = Qbf + ((size_t)cls * CPAD + (size_t)t * 16) * DDIM;
        bf16x8 bfrag[8];
        #pragma unroll
        for (int kk = 0; kk < 8; ++kk)
            bfrag[kk] = *reinterpret_cast<const bf16x8*>(qb + (size_t)lm * DDIM + kk * 32 + lg * 8);

        f32x4 acc0 = {0.f,0.f,0.f,0.f}, acc1 = {0.f,0.f,0.f,0.f};
        #pragma unroll
        for (int kk = 0; kk < 8; ++kk) {
            acc0 = __builtin_amdgcn_mfma_f32_16x16x32_bf16(afrag[0][kk], bfrag[kk], acc0, 0, 0, 0);
            acc1 = __builtin_amdgcn_mfma_f32_16x16x32_bf16(afrag[1][kk], bfrag[kk], acc1, 0, 0, 0);
        }

        int cic = t * 16 + lm;            // col within class
        bool valid = (cic < CACHE);
        #pragma unroll
        for (int f = 0; f < 2; ++f) {
            f32x4 a = f ? acc1 : acc0;
            #pragma unroll
            for (int r = 0; r < 4; ++r) {
                float s = a[r] * INVT;
                if (ispos[f][r]) {
                    if (valid) poslog[(size_t)rowidx[f][r] * CACHE + cic] = s;
                } else if (valid) {
                    negacc[f][r] += __expf(s);
                }
            }
        }
    }

    int chunk = cls * NSUB + sub;
    #pragma unroll
    for (int f = 0; f < 2; ++f)
        #pragma unroll
        for (int r = 0; r < 4; ++r) {
            float v = negacc[f][r];
            v += __shfl_xor(v, 1);
            v += __shfl_xor(v, 2);
            v += __shfl_xor(v, 4);
            v += __shfl_xor(v, 8);
            if (lm == 0) partials[(size_t)chunk * MPAD + rowidx[f][r]] = v;
        }
}

// ---- combine chunk partials -> per-row neg_sum ----
__global__ void reduce_negsum(const float* __restrict__ partials, float* __restrict__ negsum) {
    int row = blockIdx.x * blockDim.x + threadIdx.x;
    if (row >= MPAD) return;
    float s = 0.f;
    for (int c = 0; c < NCHUNK; ++c) s += partials[(size_t)c * MPAD + row];
    negsum[row] = s;
}

// ---- per-row positive term: sum_j [ log(exp(s)+ns) - s ] ----
__global__ __launch_bounds__(256) void pass2_kernel(const float* __restrict__ poslog,
                                                    const float* __restrict__ negsum,
                                                    float* __restrict__ rowloss) {
    int n = blockIdx.x;
    float ns = negsum[n];
    float local = 0.f;
    for (int j = threadIdx.x; j < CACHE; j += 256) {
        float s = poslog[(size_t)n * CACHE + j];
        local += __logf(__expf(s) + ns) - s;
    }
    #pragma unroll
    for (int m = 1; m < 64; m <<= 1) local += __shfl_xor(local, m);
    __shared__ float sb[4];
    if ((threadIdx.x & 63) == 0) sb[threadIdx.x >> 6] = local;
    __syncthreads();
    if (threadIdx.x == 0) rowloss[n] = sb[0] + sb[1] + sb[2] + sb[3];
}

// ---- final mean ----
__global__ __launch_bounds__(256) void pass3_kernel(const float* __restrict__ rowloss,
                                                    float* __restrict__ out) {
    float local = 0.f;
    for (int n = threadIdx.x; n < NROWS; n += 256) local += rowloss[n];
    #pragma unroll
    for (int m = 1; m < 64; m <<= 1) local += __shfl_xor(local, m);
    __shared__ float sb[4];
    if ((threadIdx.x & 63) == 0) sb[threadIdx.x >> 6] = local;
    __syncthreads();
    if (threadIdx.x == 0)
        out[0] = (sb[0] + sb[1] + sb[2] + sb[3]) * (1.0f / ((float)CACHE + 1e-4f)) * (1.0f / (float)NROWS);
}

extern "C" void kernel_launch(void* const* d_in, const int* in_sizes, int n_in,
                              void* d_out, int out_size, void* d_ws, size_t ws_size,
                              hipStream_t stream) {
    const float* X  = (const float*)d_in[0];   // [102][10][256]
    const int*   y  = (const int*)d_in[1];     // [102]
    const float* Qf = (const float*)d_in[2];   // [19][5000][256]
    float* out = (float*)d_out;

    char* ws = (char*)d_ws;
    // ws layout (bytes):
    //   Qbf      [19*5008][256] bf16 : 48,717,824
    //   Abf      [1024][256]   bf16 :    524,288
    //   poslog   [1024][5000]  f32  : 20,480,000
    //   partials [133][1024]   f32  :    544,768
    //   negsum   [1024]        f32  :      4,096
    //   rowloss  [1024]        f32  :      4,096
    unsigned short* Qbf   = (unsigned short*)(ws);
    unsigned short* Abf   = (unsigned short*)(ws + 48717824);
    float* poslog   = (float*)(ws + 49242112);
    float* partials = (float*)(ws + 69722112);
    float* negsum   = (float*)(ws + 70266880);
    float* rowloss  = (float*)(ws + 70270976);

    {
        size_t nthreads = (size_t)NCLS * CPAD * DDIM / 8;   // 3,044,864
        int blocks = (int)((nthreads + 255) / 256);
        conv_queue<<<blocks, 256, 0, stream>>>(Qf, Qbf);
    }
    conv_anchor<<<MPAD, DDIM, 0, stream>>>(X, Abf);
    pass1_kernel<<<4 * NCLS * NSUB, 512, 0, stream>>>(Abf, Qbf, y, partials, poslog);
    reduce_negsum<<<MPAD / 256, 256, 0, stream>>>(partials, negsum);
    pass2_kernel<<<NROWS, 256, 0, stream>>>(poslog, negsum, rowloss);
    pass3_kernel<<<1, 256, 0, stream>>>(rowloss, out);
}

// Round 3
// 144.987 us; speedup vs baseline: 1.9994x; 1.9994x over previous
//
#include <hip/hip_runtime.h>
#include <hip/hip_bf16.h>
#include <stdint.h>

// ---- problem constants ----
#define NCLS   19
#define CACHE  5000
#define NTILE  313            // 16-col tiles per class (313*16 = 5008, 8 pad cols)
#define DDIM   256
#define NANCH  102
#define NVIEW  10
#define NROWS  1020
#define NSUB   13             // column sub-chunks per class
#define NCHUNK (NCLS*NSUB)    // 247
#define SCALE_A 20.6099319733f   // (1/0.07) * log2(e): MFMA acc = s * log2(e)
#define LN2     0.69314718056f

using bf16x8 = __attribute__((ext_vector_type(8))) __bf16;
using f32x4  = __attribute__((ext_vector_type(4))) float;
using u16x8  = __attribute__((ext_vector_type(8))) unsigned short;

#if __has_builtin(__builtin_amdgcn_exp2f)
#define EXP2(x) __builtin_amdgcn_exp2f(x)
#else
#define EXP2(x) __expf((x) * LN2)
#endif

static __device__ __forceinline__ unsigned short f2bf(float x) {
    unsigned int u = __float_as_uint(x);
    unsigned int r = (u + 0x7FFFu + ((u >> 16) & 1u)) >> 16;
    return (unsigned short)r;
}

typedef const __attribute__((address_space(1))) void* gas_t;
typedef __attribute__((address_space(3))) void* las_t;

// async global->LDS: 16B per lane, dest = wave-uniform LDS base + lane*16
static __device__ __forceinline__ void stage16(const unsigned short* g, unsigned short* lw) {
    __builtin_amdgcn_global_load_lds((gas_t)(uintptr_t)g, (las_t)(uintptr_t)lw, 16, 0, 0);
}

// ---- queue f32 [19][5000][256] -> fragment-major bf16 tiles ----
// chunk i (16B) = (cls, t, kk, lane): col = t*16+(lane&15), k = kk*32+(lane>>4)*8
__global__ __launch_bounds__(256) void conv_queue2(const float* __restrict__ Qf,
                                                   unsigned short* __restrict__ Qbf) {
    int i = blockIdx.x * 256 + threadIdx.x;          // 3,044,864 chunks exactly
    int lane = i & 63;
    int kk   = (i >> 6) & 7;
    int tile = i >> 9;
    int cls  = tile / NTILE;
    int t    = tile - cls * NTILE;
    int lm = lane & 15, lg = lane >> 4;
    int cic = t * 16 + lm;
    int k   = kk * 32 + lg * 8;
    u16x8 o;
    if (cic < CACHE) {
        const float* src = Qf + ((size_t)cls * CACHE + cic) * DDIM + k;
        float4 v0 = *reinterpret_cast<const float4*>(src);
        float4 v1 = *reinterpret_cast<const float4*>(src + 4);
        o[0]=f2bf(v0.x); o[1]=f2bf(v0.y); o[2]=f2bf(v0.z); o[3]=f2bf(v0.w);
        o[4]=f2bf(v1.x); o[5]=f2bf(v1.y); o[6]=f2bf(v1.z); o[7]=f2bf(v1.w);
    } else {
        for (int q = 0; q < 8; ++q) o[q] = 0;
    }
    *reinterpret_cast<u16x8*>(Qbf + (size_t)i * 8) = o;
}

// ---- anchors: view-major [1024][256] bf16, pre-scaled by (1/T)*log2(e) ----
__global__ __launch_bounds__(256) void conv_anchor2(const float* __restrict__ X,
                                                    unsigned short* __restrict__ Abf) {
    int n = blockIdx.x;     // 0..1023
    int k = threadIdx.x;    // 0..255
    float v = 0.f;
    if (n < NROWS) {
        int vv = n / NANCH, a = n - vv * NANCH;
        v = X[((size_t)a * NVIEW + vv) * DDIM + k] * SCALE_A;
    }
    Abf[(size_t)n * DDIM + k] = f2bf(v);
}

// ---- fused pass: GEMM + exp2 + (tot, pos_e, pos_s) accumulation ----
__global__ __launch_bounds__(512) void pass1_kernel(
    const unsigned short* __restrict__ Abf, const unsigned short* __restrict__ Qbf,
    const int* __restrict__ y,
    float* __restrict__ Pt, float* __restrict__ Pe, float* __restrict__ Ps)
{
    __shared__ unsigned short lds[2][4096];   // 2 x 8KB tile buffers

    int b   = blockIdx.x;
    int rt  = b & 3;            // row tile (consecutive blocks share columns -> L2)
    int cs  = b >> 2;           // 0..246
    int cls = cs / NSUB;
    int sub = cs - cls * NSUB;
    int t0 = (NTILE * sub) / NSUB, t1 = (NTILE * (sub + 1)) / NSUB;

    int tid = threadIdx.x;
    int wave = tid >> 6, lane = tid & 63;
    int lg = lane >> 4, lm = lane & 15;
    int wrb = rt * 256 + wave * 32;

    // A fragments (log2-scaled): row = lane&15, k = kk*32 + (lane>>4)*8 + [0,8)
    bf16x8 afrag[2][8];
    #pragma unroll
    for (int f = 0; f < 2; ++f)
        #pragma unroll
        for (int kk = 0; kk < 8; ++kk)
            afrag[f][kk] = *reinterpret_cast<const bf16x8*>(
                Abf + (size_t)(wrb + f * 16 + lm) * DDIM + kk * 32 + lg * 8);

    float mpos[2][4];
    int   rowidx[2][4];
    #pragma unroll
    for (int f = 0; f < 2; ++f)
        #pragma unroll
        for (int r = 0; r < 4; ++r) {
            int row = wrb + f * 16 + lg * 4 + r;
            rowidx[f][r] = row;
            mpos[f][r] = (row < NROWS && y[row % NANCH] == cls) ? 1.0f : 0.0f;
        }

    float tacc[2][4] = {}, peacc[2][4] = {}, psacc[2][4] = {};

    const unsigned short* qcls = Qbf + (size_t)cls * NTILE * 4096;

    // prologue stage
    stage16(qcls + (size_t)t0 * 4096 + tid * 8, &lds[0][wave * 512]);
    __syncthreads();   // drains vmcnt(0): tile 0 ready

    int nt = t1 - t0;
    for (int it = 0; it < nt; ++it) {
        int cur = it & 1;
        if (it + 1 < nt)
            stage16(qcls + (size_t)(t0 + it + 1) * 4096 + tid * 8, &lds[cur ^ 1][wave * 512]);

        bf16x8 bfrag[8];
        const unsigned short* lp = &lds[cur][lane * 8];
        #pragma unroll
        for (int kk = 0; kk < 8; ++kk)
            bfrag[kk] = *reinterpret_cast<const bf16x8*>(lp + kk * 512);

        f32x4 acc0 = {0.f,0.f,0.f,0.f}, acc1 = {0.f,0.f,0.f,0.f};
        #pragma unroll
        for (int kk = 0; kk < 8; ++kk) {
            acc0 = __builtin_amdgcn_mfma_f32_16x16x32_bf16(afrag[0][kk], bfrag[kk], acc0, 0, 0, 0);
            acc1 = __builtin_amdgcn_mfma_f32_16x16x32_bf16(afrag[1][kk], bfrag[kk], acc1, 0, 0, 0);
        }

        #pragma unroll
        for (int f = 0; f < 2; ++f) {
            f32x4 a = f ? acc1 : acc0;
            #pragma unroll
            for (int r = 0; r < 4; ++r) {
                float v = a[r];                // s * log2(e)
                float e = EXP2(v);             // e^s   (pad cols: v=0 -> e=1, fixed at reduce)
                tacc[f][r]  += e;
                peacc[f][r] += mpos[f][r] * e;
                psacc[f][r] += mpos[f][r] * v;
            }
        }
        __syncthreads();   // drains this iter's stage; buffers safe to swap
    }

    // reduce across the 16 column-lanes (lm) and store per-chunk partials
    #pragma unroll
    for (int f = 0; f < 2; ++f)
        #pragma unroll
        for (int r = 0; r < 4; ++r) {
            float t = tacc[f][r], e = peacc[f][r], s = psacc[f][r];
            #pragma unroll
            for (int m = 1; m < 16; m <<= 1) {
                t += __shfl_xor(t, m);
                e += __shfl_xor(e, m);
                s += __shfl_xor(s, m);
            }
            if (lm == 0) {
                size_t idx = (size_t)cs * 1024 + rowidx[f][r];
                Pt[idx] = t; Pe[idx] = e; Ps[idx] = s;
            }
        }
}

// ---- per-row finalization ----
__global__ __launch_bounds__(256) void reduce_rows(const float* __restrict__ Pt,
                                                   const float* __restrict__ Pe,
                                                   const float* __restrict__ Ps,
                                                   float* __restrict__ rowloss) {
    int row = blockIdx.x * 256 + threadIdx.x;   // 0..1023
    float tot = 0.f, pe = 0.f, ps = 0.f;
    for (int c = 0; c < NCHUNK; ++c) {
        size_t idx = (size_t)c * 1024 + row;
        tot += Pt[idx]; pe += Pe[idx]; ps += Ps[idx];
    }
    float r = 0.f;
    if (row < NROWS) {
        // tot includes all 19*8=152 pad cols (e=1 each); pe includes the 8 pads of the pos class
        float ns    = tot - pe - 144.0f;        // sum of exp over true negatives
        float pos_e = pe - 8.0f;                // sum of exp over true positives
        float pos_s = ps * LN2;                 // sum of s over positives (ln domain)
        // sum_pos log(e^s + ns) ~= 5000*log(ns) + pos_e/ns   (first-order log1p, x<=~3e-3)
        float sum_logprob = pos_s - (5000.0f * logf(ns) + pos_e / ns);
        r = -sum_logprob / (5000.0f + 1e-4f);
    }
    rowloss[row] = r;
}

// ---- final mean over 1020 rows ----
__global__ __launch_bounds__(256) void pass3_kernel(const float* __restrict__ rowloss,
                                                    float* __restrict__ out) {
    float local = 0.f;
    for (int n = threadIdx.x; n < 1024; n += 256) local += rowloss[n];
    #pragma unroll
    for (int m = 1; m < 64; m <<= 1) local += __shfl_xor(local, m);
    __shared__ float sb[4];
    if ((threadIdx.x & 63) == 0) sb[threadIdx.x >> 6] = local;
    __syncthreads();
    if (threadIdx.x == 0)
        out[0] = (sb[0] + sb[1] + sb[2] + sb[3]) * (1.0f / (float)NROWS);
}

extern "C" void kernel_launch(void* const* d_in, const int* in_sizes, int n_in,
                              void* d_out, int out_size, void* d_ws, size_t ws_size,
                              hipStream_t stream) {
    const float* X  = (const float*)d_in[0];   // [102][10][256]
    const int*   y  = (const int*)d_in[1];     // [102]
    const float* Qf = (const float*)d_in[2];   // [19][5000][256]
    float* out = (float*)d_out;

    char* ws = (char*)d_ws;
    // ws layout (bytes):
    //   Qbf [19*313 tiles][8KB]        : 48,717,824
    //   Abf [1024][256] bf16           :    524,288
    //   Pt  [247][1024] f32            :  1,011,712
    //   Pe  [247][1024] f32            :  1,011,712
    //   Ps  [247][1024] f32            :  1,011,712
    //   rowloss [1024] f32             :      4,096
    unsigned short* Qbf = (unsigned short*)(ws);
    unsigned short* Abf = (unsigned short*)(ws + 48717824);
    float* Pt      = (float*)(ws + 49242112);
    float* Pe      = (float*)(ws + 50253824);
    float* Ps      = (float*)(ws + 51265536);
    float* rowloss = (float*)(ws + 52277248);

    conv_queue2<<<11894, 256, 0, stream>>>(Qf, Qbf);       // 3,044,864 chunks
    conv_anchor2<<<1024, 256, 0, stream>>>(X, Abf);
    pass1_kernel<<<4 * NCHUNK, 512, 0, stream>>>(Abf, Qbf, y, Pt, Pe, Ps);  // 988 blocks
    reduce_rows<<<4, 256, 0, stream>>>(Pt, Pe, Ps, rowloss);
    pass3_kernel<<<1, 256, 0, stream>>>(rowloss, out);
}

// Round 4
// 111.764 us; speedup vs baseline: 2.5937x; 1.2973x over previous
//
#include <hip/hip_runtime.h>
#include <hip/hip_bf16.h>
#include <stdint.h>

// ---- problem constants ----
#define NCLS   19
#define CACHE  5000
#define NTILE  313            // 16-col tiles per class (313*16 = 5008, 8 pad cols)
#define DDIM   256
#define NANCH  102
#define NVIEW  10
#define NROWS  1020
#define NSUB   13             // column sub-chunks per class
#define NCHUNK (NCLS*NSUB)    // 247
#define NWG    (4*NCHUNK)     // 988 pass1 blocks
#define SCALE_A 20.6099319733f   // (1/0.07) * log2(e): MFMA acc = s * log2(e)
#define LN2     0.69314718056f

using bf16x8 = __attribute__((ext_vector_type(8))) __bf16;
using f32x4  = __attribute__((ext_vector_type(4))) float;
using u16x8  = __attribute__((ext_vector_type(8))) unsigned short;

#if __has_builtin(__builtin_amdgcn_exp2f)
#define EXP2(x) __builtin_amdgcn_exp2f(x)
#else
#define EXP2(x) __expf((x) * LN2)
#endif

static __device__ __forceinline__ unsigned short f2bf(float x) {
    unsigned int u = __float_as_uint(x);
    unsigned int r = (u + 0x7FFFu + ((u >> 16) & 1u)) >> 16;
    return (unsigned short)r;
}

typedef const __attribute__((address_space(1))) void* gas_t;
typedef __attribute__((address_space(3))) void* las_t;

// async global->LDS: 16B per lane, dest = wave-uniform LDS base + lane*16
static __device__ __forceinline__ void stage16(const unsigned short* g, unsigned short* lw) {
    __builtin_amdgcn_global_load_lds((gas_t)(uintptr_t)g, (las_t)(uintptr_t)lw, 16, 0, 0);
}

// ---- queue f32 [19][5000][256] -> fragment-major bf16 tiles ----
// chunk i (16B) = (cls, t, kk, lane): col = t*16+(lane&15), k = kk*32+(lane>>4)*8
__global__ __launch_bounds__(256) void conv_queue2(const float* __restrict__ Qf,
                                                   unsigned short* __restrict__ Qbf) {
    int i = blockIdx.x * 256 + threadIdx.x;          // 3,044,864 chunks exactly
    int lane = i & 63;
    int kk   = (i >> 6) & 7;
    int tile = i >> 9;
    int cls  = tile / NTILE;
    int t    = tile - cls * NTILE;
    int lm = lane & 15, lg = lane >> 4;
    int cic = t * 16 + lm;
    int k   = kk * 32 + lg * 8;
    u16x8 o;
    if (cic < CACHE) {
        const float* src = Qf + ((size_t)cls * CACHE + cic) * DDIM + k;
        float4 v0 = *reinterpret_cast<const float4*>(src);
        float4 v1 = *reinterpret_cast<const float4*>(src + 4);
        o[0]=f2bf(v0.x); o[1]=f2bf(v0.y); o[2]=f2bf(v0.z); o[3]=f2bf(v0.w);
        o[4]=f2bf(v1.x); o[5]=f2bf(v1.y); o[6]=f2bf(v1.z); o[7]=f2bf(v1.w);
    } else {
        for (int q = 0; q < 8; ++q) o[q] = 0;
    }
    *reinterpret_cast<u16x8*>(Qbf + (size_t)i * 8) = o;
}

// ---- anchors: view-major [1024][256] bf16, pre-scaled by (1/T)*log2(e) ----
__global__ __launch_bounds__(256) void conv_anchor2(const float* __restrict__ X,
                                                    unsigned short* __restrict__ Abf) {
    int n = blockIdx.x;     // 0..1023
    int k = threadIdx.x;    // 0..255
    float v = 0.f;
    if (n < NROWS) {
        int vv = n / NANCH, a = n - vv * NANCH;
        v = X[((size_t)a * NVIEW + vv) * DDIM + k] * SCALE_A;
    }
    Abf[(size_t)n * DDIM + k] = f2bf(v);
}

// ---- fused pass: GEMM + exp2 + (tot, sum_s) accumulation, 64 rows/wave ----
__global__ __launch_bounds__(256, 2) void pass1_kernel(
    const unsigned short* __restrict__ Abf, const unsigned short* __restrict__ Qbf,
    const int* __restrict__ y,
    float* __restrict__ Pt, float* __restrict__ Pe, float* __restrict__ Ps)
{
    __shared__ unsigned short lds[2][4096];   // 2 x 8KB tile buffers

    // bijective XCD swizzle (m204): nwg=988, 8 XCDs, q=123, r=4.
    // Work id is rt-minor so all 4 row-tiles of a column chunk share an XCD/L2.
    int orig = blockIdx.x;
    int xcd = orig & 7, slot = orig >> 3;
    int wid = (xcd < 4 ? xcd * 124 : 496 + (xcd - 4) * 123) + slot;
    int rt = wid & 3;           // row tile (256 rows)
    int cs = wid >> 2;          // 0..246 column chunk
    int cls = cs / NSUB;
    int sub = cs - cls * NSUB;
    int t0 = (NTILE * sub) / NSUB, t1 = (NTILE * (sub + 1)) / NSUB;

    int tid = threadIdx.x;
    int wave = tid >> 6, lane = tid & 63;
    int lg = lane >> 4, lm = lane & 15;
    int wrb = rt * 256 + wave * 64;   // this wave owns rows [wrb, wrb+64)

    // A fragments (log2-scaled): frag f covers rows wrb+f*16, row-in-frag = lane&15
    bf16x8 afrag[4][8];
    #pragma unroll
    for (int f = 0; f < 4; ++f)
        #pragma unroll
        for (int kk = 0; kk < 8; ++kk)
            afrag[f][kk] = *reinterpret_cast<const bf16x8*>(
                Abf + (size_t)(wrb + f * 16 + lm) * DDIM + kk * 32 + lg * 8);

    float mpos[4][4];
    int   rowidx[4][4];
    #pragma unroll
    for (int f = 0; f < 4; ++f)
        #pragma unroll
        for (int r = 0; r < 4; ++r) {
            int row = wrb + f * 16 + lg * 4 + r;
            rowidx[f][r] = row;
            mpos[f][r] = (row < NROWS && y[row % NANCH] == cls) ? 1.0f : 0.0f;
        }

    float tacc[4][4] = {}, sacc[4][4] = {};

    const unsigned short* qcls = Qbf + (size_t)cls * NTILE * 4096;

#define STAGE(buf, t) do {                                                        \
        stage16(qcls + (size_t)(t) * 4096 + tid * 8,        &lds[buf][wave * 512]);        \
        stage16(qcls + (size_t)(t) * 4096 + 2048 + tid * 8, &lds[buf][2048 + wave * 512]); \
    } while (0)

    STAGE(0, t0);
    __syncthreads();   // drains vmcnt(0): tile 0 ready

    int nt = t1 - t0;
    for (int it = 0; it < nt; ++it) {
        int cur = it & 1;
        if (it + 1 < nt) STAGE(cur ^ 1, t0 + it + 1);

        bf16x8 bfrag[8];
        const unsigned short* lp = &lds[cur][lane * 8];
        #pragma unroll
        for (int kk = 0; kk < 8; ++kk)
            bfrag[kk] = *reinterpret_cast<const bf16x8*>(lp + kk * 512);

        f32x4 acc[4];
        #pragma unroll
        for (int f = 0; f < 4; ++f) acc[f] = (f32x4){0.f, 0.f, 0.f, 0.f};
        #pragma unroll
        for (int kk = 0; kk < 8; ++kk)
            #pragma unroll
            for (int f = 0; f < 4; ++f)
                acc[f] = __builtin_amdgcn_mfma_f32_16x16x32_bf16(afrag[f][kk], bfrag[kk], acc[f], 0, 0, 0);

        // epilogue: only (sum e, sum v); pos masking applied once at write time
        #pragma unroll
        for (int f = 0; f < 4; ++f)
            #pragma unroll
            for (int r = 0; r < 4; ++r) {
                float v = acc[f][r];           // s * log2(e)
                tacc[f][r] += EXP2(v);         // pad cols: v=0 -> e=1, fixed at reduce
                sacc[f][r] += v;
            }
        __syncthreads();   // this iter's stage complete; swap buffers
    }
#undef STAGE

    // reduce across the 16 column-lanes (lm) and store per-chunk partials
    #pragma unroll
    for (int f = 0; f < 4; ++f)
        #pragma unroll
        for (int r = 0; r < 4; ++r) {
            float t = tacc[f][r], s = sacc[f][r];
            #pragma unroll
            for (int m = 1; m < 16; m <<= 1) {
                t += __shfl_xor(t, m);
                s += __shfl_xor(s, m);
            }
            if (lm == 0) {
                size_t idx = (size_t)cs * 1024 + rowidx[f][r];
                float mp = mpos[f][r];
                Pt[idx] = t; Pe[idx] = mp * t; Ps[idx] = mp * s;
            }
        }
}

// ---- per-row finalization: 16 blocks x 256 thr, 4 threads per row ----
__global__ __launch_bounds__(256) void reduce_rows(const float* __restrict__ Pt,
                                                   const float* __restrict__ Pe,
                                                   const float* __restrict__ Ps,
                                                   float* __restrict__ rowloss) {
    int tid = threadIdx.x;
    int row = blockIdx.x * 64 + (tid >> 2);   // 0..1023
    int part = tid & 3;
    float tot = 0.f, pe = 0.f, ps = 0.f;
    for (int c = part; c < NCHUNK; c += 4) {
        size_t idx = (size_t)c * 1024 + row;
        tot += Pt[idx]; pe += Pe[idx]; ps += Ps[idx];
    }
    tot += __shfl_xor(tot, 1); pe += __shfl_xor(pe, 1); ps += __shfl_xor(ps, 1);
    tot += __shfl_xor(tot, 2); pe += __shfl_xor(pe, 2); ps += __shfl_xor(ps, 2);
    if (part == 0) {
        float r = 0.f;
        if (row < NROWS) {
            // tot includes all 19*8=152 pad cols (e=1 each); pe includes the 8 pads of the pos class
            float ns    = tot - pe - 144.0f;        // sum of exp over true negatives
            float pos_e = pe - 8.0f;                // sum of exp over true positives
            float pos_s = ps * LN2;                 // sum of s over positives (ln domain)
            // sum_pos log(e^s + ns) ~= 5000*log(ns) + pos_e/ns   (first-order log1p)
            float sum_logprob = pos_s - (5000.0f * logf(ns) + pos_e / ns);
            r = -sum_logprob / (5000.0f + 1e-4f);
        }
        rowloss[row] = r;
    }
}

// ---- final mean over 1020 rows ----
__global__ __launch_bounds__(256) void pass3_kernel(const float* __restrict__ rowloss,
                                                    float* __restrict__ out) {
    float local = 0.f;
    for (int n = threadIdx.x; n < 1024; n += 256) local += rowloss[n];
    #pragma unroll
    for (int m = 1; m < 64; m <<= 1) local += __shfl_xor(local, m);
    __shared__ float sb[4];
    if ((threadIdx.x & 63) == 0) sb[threadIdx.x >> 6] = local;
    __syncthreads();
    if (threadIdx.x == 0)
        out[0] = (sb[0] + sb[1] + sb[2] + sb[3]) * (1.0f / (float)NROWS);
}

extern "C" void kernel_launch(void* const* d_in, const int* in_sizes, int n_in,
                              void* d_out, int out_size, void* d_ws, size_t ws_size,
                              hipStream_t stream) {
    const float* X  = (const float*)d_in[0];   // [102][10][256]
    const int*   y  = (const int*)d_in[1];     // [102]
    const float* Qf = (const float*)d_in[2];   // [19][5000][256]
    float* out = (float*)d_out;

    char* ws = (char*)d_ws;
    // ws layout (bytes):
    //   Qbf [19*313 tiles][8KB]        : 48,717,824
    //   Abf [1024][256] bf16           :    524,288
    //   Pt  [247][1024] f32            :  1,011,712
    //   Pe  [247][1024] f32            :  1,011,712
    //   Ps  [247][1024] f32            :  1,011,712
    //   rowloss [1024] f32             :      4,096
    unsigned short* Qbf = (unsigned short*)(ws);
    unsigned short* Abf = (unsigned short*)(ws + 48717824);
    float* Pt      = (float*)(ws + 49242112);
    float* Pe      = (float*)(ws + 50253824);
    float* Ps      = (float*)(ws + 51265536);
    float* rowloss = (float*)(ws + 52277248);

    conv_queue2<<<11894, 256, 0, stream>>>(Qf, Qbf);       // 3,044,864 chunks
    conv_anchor2<<<1024, 256, 0, stream>>>(X, Abf);
    pass1_kernel<<<NWG, 256, 0, stream>>>(Abf, Qbf, y, Pt, Pe, Ps);  // 988 blocks
    reduce_rows<<<16, 256, 0, stream>>>(Pt, Pe, Ps, rowloss);
    pass3_kernel<<<1, 256, 0, stream>>>(rowloss, out);
}